// Round 16
// baseline (433.440 us; speedup 1.0000x reference)
//
#include <hip/hip_runtime.h>
#include <stdint.h>

#define NB 32768

typedef __bf16 bf16x8 __attribute__((ext_vector_type(8)));
typedef float f32x4 __attribute__((ext_vector_type(4)));

// native packed f32->bf16 (RNE, compiles to v_cvt_pk_bf16_f32)
__device__ __forceinline__ unsigned pack_bf2(float a, float b) {
  union { __bf16 h[2]; unsigned u; } t;
  t.h[0] = (__bf16)a; t.h[1] = (__bf16)b;
  return t.u;
}
__device__ __forceinline__ unsigned short bf16b(float f) {
  union { __bf16 h; unsigned short u; } t;
  t.h = (__bf16)f;
  return t.u;
}
__device__ __forceinline__ float bf2f(unsigned short h) {
  union { unsigned u; float f; } v; v.u = ((unsigned)h) << 16;
  return v.f;
}

// global -> LDS direct copy, 16B per lane. LDS dest is wave-uniform base + lane*16.
__device__ __forceinline__ void gld_lds16(void* lds, const void* g) {
  __builtin_amdgcn_global_load_lds(
      (__attribute__((address_space(1))) unsigned int*)(uintptr_t)g,
      (__attribute__((address_space(3))) unsigned int*)(uintptr_t)lds,
      16, 0, 0);
}

// XCD-chunk swizzle (nwg % 8 == 0): contiguous wgid chunks land on one XCD.
__device__ __forceinline__ int xcd_swz(int bid, int nwg) {
  return (bid & 7) * (nwg >> 3) + (bid >> 3);
}

// ---------------- prep kernels ----------------

__global__ __launch_bounds__(256) void fconv_k(const float* __restrict__ src,
                                               unsigned short* __restrict__ dst) {
  size_t idx = ((size_t)blockIdx.x * 256 + threadIdx.x) * 8;
  float4 a = *(const float4*)(src + idx);
  float4 b = *(const float4*)(src + idx + 4);
  uint4 o;
  o.x = pack_bf2(a.x, a.y); o.y = pack_bf2(a.z, a.w);
  o.z = pack_bf2(b.x, b.y); o.w = pack_bf2(b.z, b.w);
  *(uint4*)(dst + idx) = o;
}

// bias concat: dst[0:512]=a, dst[512:1024]=b
__global__ __launch_bounds__(256) void bcat_k(const float* __restrict__ a,
                                              const float* __restrict__ b,
                                              float* __restrict__ dst) {
  const int i = blockIdx.x * 256 + threadIdx.x;
  dst[i] = (i < 512) ? a[i] : b[i - 512];
}

struct TJobs {
  const float* src[11];
  unsigned short* dst[11];
  int K[11], N[11], batch[11];
};

// transpose fp32 [K][N] -> bf16 [N][K], batched, 32x32 tiles
__global__ __launch_bounds__(256) void wtrans_k(TJobs jobs) {
  const int job = blockIdx.y;
  const int K = jobs.K[job], N = jobs.N[job];
  const int KT = K >> 5, NT = N >> 5;
  const int ntiles = jobs.batch[job] * KT * NT;
  const int t = blockIdx.x;
  if (t >= ntiles) return;
  const int b = t / (KT * NT);
  const int rem = t - b * KT * NT;
  const int kt = rem / NT, nt = rem - kt * NT;
  const float* src = jobs.src[job] + (size_t)b * K * N;
  unsigned short* dst = jobs.dst[job] + (size_t)b * K * N;
  __shared__ float tile[32][33];
  const int i = threadIdx.x >> 5, jj = threadIdx.x & 31;
#pragma unroll
  for (int s = 0; s < 4; ++s)
    tile[i + 8 * s][jj] = src[(size_t)(kt * 32 + i + 8 * s) * N + nt * 32 + jj];
  __syncthreads();
#pragma unroll
  for (int s = 0; s < 4; ++s)
    dst[(size_t)(nt * 32 + i + 8 * s) * K + kt * 32 + jj] = bf16b(tile[jj][i + 8 * s]);
}

// ---------------- wide GEMM (N>=512): 128x256 tile, BK=32 ----------------
// 3-buffer LDS ring, 2-deep prefetch, counted vmcnt (R11-verified).

template <bool OUT_BF16>
__global__ __launch_bounds__(256, 2) void gemm2_k(const unsigned short* __restrict__ A, int lda,
                                                  const unsigned short* __restrict__ WT,
                                                  const float* __restrict__ bias,
                                                  void* __restrict__ Cout, int ldc, int K,
                                                  int ncl2) {
  __shared__ unsigned short a_s[3][128 * 32];  // [row][slot], slot = c ^ ((row>>1)&3)
  __shared__ unsigned short b_s[3][256 * 32];  // [n][slot]
  const int tid = threadIdx.x;
  const int l = tid & 63, w = tid >> 6;   // w = wn 0..3
  const int lr = l & 15, lq = l >> 4;
  const int wg = xcd_swz(blockIdx.x, gridDim.x);
  const int col0 = (wg & ((1 << ncl2) - 1)) << 8;
  const int row0 = (wg >> ncl2) << 7;
  const int wbase = tid & ~63;

  auto stage = [&](int t) {
    const int buf = t % 3;
    const int k0 = t << 5;
#pragma unroll
    for (int i = 0; i < 2; ++i) {  // A: 512 slots
      const int s = i * 256 + tid;
      const int r = s >> 2, c = s & 3;
      const int cs = c ^ ((r >> 1) & 3);
      gld_lds16(&a_s[buf][(size_t)(i * 256 + wbase) * 8],
                A + (size_t)(row0 + r) * lda + k0 + cs * 8);
    }
#pragma unroll
    for (int i = 0; i < 4; ++i) {  // B: 1024 slots
      const int s = i * 256 + tid;
      const int n = s >> 2, c = s & 3;
      const int cs = c ^ ((n >> 1) & 3);
      gld_lds16(&b_s[buf][(size_t)(i * 256 + wbase) * 8],
                WT + (size_t)(col0 + n) * K + k0 + cs * 8);
    }
  };

  f32x4 acc[8][4] = {};
  const int nt = K >> 5;
  stage(0);
  stage(1);
#pragma unroll 1
  for (int t = 0; t < nt; ++t) {
    if (t + 1 < nt) asm volatile("s_waitcnt vmcnt(6)" ::: "memory");
    else            asm volatile("s_waitcnt vmcnt(0)" ::: "memory");
    __builtin_amdgcn_s_barrier();
    if (t + 2 < nt) stage(t + 2);
    const int cur = t % 3;
    bf16x8 av[8], bv[4];
#pragma unroll
    for (int mf = 0; mf < 8; ++mf) {
      const int r = mf * 16 + lr;
      av[mf] = *(const bf16x8*)&a_s[cur][r * 32 + ((lq ^ ((r >> 1) & 3)) << 3)];
    }
#pragma unroll
    for (int nf = 0; nf < 4; ++nf) {
      const int n = w * 64 + nf * 16 + lr;
      bv[nf] = *(const bf16x8*)&b_s[cur][n * 32 + ((lq ^ ((n >> 1) & 3)) << 3)];
    }
#pragma unroll
    for (int mf = 0; mf < 8; ++mf)
#pragma unroll
      for (int nf = 0; nf < 4; ++nf)
        acc[mf][nf] = __builtin_amdgcn_mfma_f32_16x16x32_bf16(av[mf], bv[nf], acc[mf][nf], 0, 0, 0);
  }

#pragma unroll
  for (int nf = 0; nf < 4; ++nf) {
    const int gc = col0 + w * 64 + nf * 16 + lr;
    const float bb = bias[gc];
#pragma unroll
    for (int mf = 0; mf < 8; ++mf) {
      const int gr = row0 + mf * 16 + (lq << 2);
#pragma unroll
      for (int r = 0; r < 4; ++r) {
        float v = acc[mf][nf][r] + bb;
        v = fmaxf(v, 0.0f);
        if (OUT_BF16)
          ((unsigned short*)Cout)[(size_t)(gr + r) * ldc + gc] = bf16b(v);
        else
          ((float*)Cout)[(size_t)(gr + r) * ldc + gc] = v;
      }
    }
  }
}

// ---------------- narrow GEMM (N=256): 128x128 tile, BK=32 ----------------
// 3-buffer ring + counted vmcnt (stage = 4 loads -> vmcnt(4)).

template <bool OUT_BF16>
__global__ __launch_bounds__(256, 2) void gemm3_k(const unsigned short* __restrict__ A, int lda,
                                                  const unsigned short* __restrict__ WT,
                                                  const float* __restrict__ bias,
                                                  void* __restrict__ Cout, int ldc, int K,
                                                  int ncl2) {
  __shared__ unsigned short a_s[3][128 * 32];
  __shared__ unsigned short b_s[3][128 * 32];
  const int tid = threadIdx.x;
  const int l = tid & 63, w = tid >> 6;
  const int wm = w >> 1, wn = w & 1;
  const int lr = l & 15, lq = l >> 4;
  const int wg = xcd_swz(blockIdx.x, gridDim.x);
  const int col0 = (wg & ((1 << ncl2) - 1)) << 7;
  const int row0 = (wg >> ncl2) << 7;
  const int wbase = tid & ~63;

  auto stage = [&](int t) {
    const int buf = t % 3;
    const int k0 = t << 5;
#pragma unroll
    for (int i = 0; i < 2; ++i) {  // A: 512 slots
      const int s = i * 256 + tid;
      const int r = s >> 2, c = s & 3;
      const int cs = c ^ ((r >> 1) & 3);
      gld_lds16(&a_s[buf][(size_t)(i * 256 + wbase) * 8],
                A + (size_t)(row0 + r) * lda + k0 + cs * 8);
    }
#pragma unroll
    for (int i = 0; i < 2; ++i) {  // B: 512 slots
      const int s = i * 256 + tid;
      const int n = s >> 2, c = s & 3;
      const int cs = c ^ ((n >> 1) & 3);
      gld_lds16(&b_s[buf][(size_t)(i * 256 + wbase) * 8],
                WT + (size_t)(col0 + n) * K + k0 + cs * 8);
    }
  };

  f32x4 acc[4][4] = {};
  const int nt = K >> 5;
  stage(0);
  stage(1);
#pragma unroll 1
  for (int t = 0; t < nt; ++t) {
    if (t + 1 < nt) asm volatile("s_waitcnt vmcnt(4)" ::: "memory");
    else            asm volatile("s_waitcnt vmcnt(0)" ::: "memory");
    __builtin_amdgcn_s_barrier();
    if (t + 2 < nt) stage(t + 2);
    const int cur = t % 3;
    bf16x8 av[4], bv[4];
#pragma unroll
    for (int mf = 0; mf < 4; ++mf) {
      const int r = wm * 64 + mf * 16 + lr;
      av[mf] = *(const bf16x8*)&a_s[cur][r * 32 + ((lq ^ ((r >> 1) & 3)) << 3)];
    }
#pragma unroll
    for (int nf = 0; nf < 4; ++nf) {
      const int n = wn * 64 + nf * 16 + lr;
      bv[nf] = *(const bf16x8*)&b_s[cur][n * 32 + ((lq ^ ((n >> 1) & 3)) << 3)];
    }
#pragma unroll
    for (int mf = 0; mf < 4; ++mf)
#pragma unroll
      for (int nf = 0; nf < 4; ++nf)
        acc[mf][nf] = __builtin_amdgcn_mfma_f32_16x16x32_bf16(av[mf], bv[nf], acc[mf][nf], 0, 0, 0);
  }

#pragma unroll
  for (int nf = 0; nf < 4; ++nf) {
    const int gc = col0 + wn * 64 + nf * 16 + lr;
    const float bb = bias[gc];
#pragma unroll
    for (int mf = 0; mf < 4; ++mf) {
      const int gr = row0 + wm * 64 + mf * 16 + (lq << 2);
#pragma unroll
      for (int r = 0; r < 4; ++r) {
        float v = acc[mf][nf][r] + bb;
        v = fmaxf(v, 0.0f);
        if (OUT_BF16)
          ((unsigned short*)Cout)[(size_t)(gr + r) * ldc + gc] = bf16b(v);
        else
          ((float*)Cout)[(size_t)(gr + r) * ldc + gc] = v;
      }
    }
  }
}

// ---------------- gate head 2: weights = sigmoid(gate_h @ gt_w2 + gt_b2), N=16 ----------------

__global__ __launch_bounds__(256) void gt2_k(const unsigned short* __restrict__ gate_h,
                                             const float* __restrict__ w2,
                                             const float* __restrict__ b2,
                                             float* __restrict__ wgt) {
  __shared__ float w_s[256 * 16];
  __shared__ unsigned short a_s[16 * 264];
  const int tid = threadIdx.x;
  const int row0 = blockIdx.x * 16;
  for (int i = tid; i < 256 * 16; i += 256) w_s[i] = w2[i];
  for (int i = tid; i < 512; i += 256) {
    const int r = i >> 5, cg = i & 31;
    *(uint4*)&a_s[r * 264 + cg * 8] =
        *(const uint4*)(gate_h + (size_t)(row0 + r) * 256 + cg * 8);
  }
  __syncthreads();
  const int rr = tid >> 4, col = tid & 15;
  float sum = b2[col];
#pragma unroll 8
  for (int k = 0; k < 256; ++k)
    sum += bf2f(a_s[rr * 264 + k]) * w_s[k * 16 + col];
  wgt[(size_t)(row0 + rr) * 16 + col] = 1.0f / (1.0f + __expf(-sum));
}

// ---------------- primitive head: per (row-tile, p-group) block ----------------
// R16: R12-verified structure + (a) seam counted waits: at t==0/t==8 the only
// loads after stage_ab(t) are the 2 pw2 loads -> vmcnt(2) (pw2 retire is
// guaranteed by the next step's vmcnt(0), well before phase2 reads pw2_s);
// (b) s_setprio(1) around MFMA clusters (2 independent blocks/CU arbitrate).

__global__ __launch_bounds__(512, 4) void prim_head_k(
    const unsigned short* __restrict__ prim,   // [B][256] bf16
    const float* __restrict__ wgt,             // [B][16]
    const unsigned short* __restrict__ pw1t,   // [16][256n][256k] bf16
    const float* __restrict__ pb1,             // [16][256]
    const unsigned short* __restrict__ pw2t,   // [16][64d][256k] bf16
    const float* __restrict__ pb2,             // [16][64]
    float* __restrict__ outbuf)                // [B][2][64] fp32
{
  __shared__ unsigned short prim_s[2][128 * 32];  // 2x8KB [row][kc], chunk kc^((rw>>1)&3)
  __shared__ unsigned short w1_s[2][128 * 32];    // 2x8KB [n_loc][kc], chunk kc^((n>>1)&3)
  __shared__ unsigned short h_s[128 * 128];       // 32KB  [row][n_loc], chunk g at g^(row&7)
  __shared__ unsigned short pw2_s[64 * 128];      // 16KB  [d][k_loc],  chunk g at g^(d&7)
  const int tid = threadIdx.x;
  const int l = tid & 63;
  const int w = tid >> 6;
  const int lr = l & 15, lq = l >> 4;
  const int wn2 = w & 1, wr2 = w >> 1;
  const int row0 = blockIdx.x << 7;
  const int pg = blockIdx.y;           // 0..1
  const int p0 = pg << 3;
  const int wbase = tid & ~63;

  auto stage_ab = [&](const unsigned short* w1p_, int t) {
    const int buf = t & 1;
    const int k0 = (t & 7) << 5;
    const int nb2 = (t >> 3) << 7;
    const int rw = tid >> 2, kc = tid & 3;
    const int kcs = kc ^ ((rw >> 1) & 3);
    gld_lds16(&prim_s[buf][(size_t)wbase * 8],
              prim + (size_t)(row0 + rw) * 256 + k0 + kcs * 8);
    gld_lds16(&w1_s[buf][(size_t)wbase * 8],
              w1p_ + (size_t)(nb2 + rw) * 256 + k0 + kcs * 8);
  };
  auto stage_pw2 = [&](const unsigned short* w2p_, int half) {
    const int nbase = half << 7;
#pragma unroll
    for (int i = 0; i < 2; ++i) {
      const int c = i * 512 + tid;
      const int d = c >> 4, kc = c & 15;
      gld_lds16(&pw2_s[(size_t)(i * 512 + wbase) * 8],
                w2p_ + (size_t)d * 256 + nbase + ((kc ^ (d & 7)) << 3));
    }
  };

  stage_ab(pw1t + (size_t)p0 * 65536, 0);
  stage_pw2(pw2t + (size_t)p0 * 16384, 0);

  f32x4 num[2] = {}, den[2] = {};

#pragma unroll 1
  for (int pi = 0; pi < 8; ++pi) {
    const int p = p0 + pi;
    const unsigned short* w1p = pw1t + (size_t)p * 65536;
    const unsigned short* w2p = pw2t + (size_t)p * 16384;

    f32x4 acc2[2][2] = {};

    for (int half = 0; half < 2; ++half) {
      float4 pb1v[4];
#pragma unroll
      for (int nf = 0; nf < 4; ++nf)
        pb1v[nf] = *(const float4*)(pb1 + p * 256 + (half << 7) + wn2 * 64 + nf * 16 + (lq << 2));

      f32x4 acc1[4][2] = {};
#pragma unroll 1
      for (int ks = 0; ks < 8; ++ks) {
        const int t = (half << 3) + ks;
        const int cur = t & 1;
        // seam steps (t==0/t==8): only the 2 pw2 loads follow stage_ab(t) ->
        // vmcnt(2) retires stage_ab(t) and keeps pw2 in flight (retired by the
        // next step's vmcnt(0), before any pw2_s ds_read).
        if (t == 0 || t == 8) asm volatile("s_waitcnt vmcnt(2)" ::: "memory");
        else                  asm volatile("s_waitcnt vmcnt(0)" ::: "memory");
        __builtin_amdgcn_s_barrier();
        if (t < 15) stage_ab(w1p, t + 1);
        else if (pi < 7) stage_ab(w1p + 65536, 0);
        bf16x8 av[4], bv[2];
#pragma unroll
        for (int nf = 0; nf < 4; ++nf) {
          const int n = wn2 * 64 + nf * 16 + lr;
          av[nf] = *(const bf16x8*)&w1_s[cur][n * 32 + ((lq ^ ((n >> 1) & 3)) << 3)];
        }
#pragma unroll
        for (int rf = 0; rf < 2; ++rf) {
          const int r = wr2 * 32 + rf * 16 + lr;
          bv[rf] = *(const bf16x8*)&prim_s[cur][r * 32 + ((lq ^ ((r >> 1) & 3)) << 3)];
        }
        __builtin_amdgcn_s_setprio(1);
#pragma unroll
        for (int nf = 0; nf < 4; ++nf)
#pragma unroll
          for (int rf = 0; rf < 2; ++rf)
            acc1[nf][rf] = __builtin_amdgcn_mfma_f32_16x16x32_bf16(av[nf], bv[rf], acc1[nf][rf], 0, 0, 0);
        __builtin_amdgcn_s_setprio(0);
      }

      // h write (ds_write); visible via lgkmcnt only (global stages stay in flight)
#pragma unroll
      for (int nf = 0; nf < 4; ++nf) {
        const int n0 = wn2 * 64 + nf * 16 + (lq << 2);
        const float4 bb = pb1v[nf];
#pragma unroll
        for (int rf = 0; rf < 2; ++rf) {
          const int row = wr2 * 32 + rf * 16 + lr;
          uint2 pk;
          pk.x = pack_bf2(fmaxf(acc1[nf][rf][0] + bb.x, 0.0f),
                          fmaxf(acc1[nf][rf][1] + bb.y, 0.0f));
          pk.y = pack_bf2(fmaxf(acc1[nf][rf][2] + bb.z, 0.0f),
                          fmaxf(acc1[nf][rf][3] + bb.w, 0.0f));
          *(uint2*)&h_s[row * 128 + (((n0 >> 3) ^ (row & 7)) << 3) + (n0 & 7)] = pk;
        }
      }
      asm volatile("s_waitcnt lgkmcnt(0)" ::: "memory");
      __builtin_amdgcn_s_barrier();

      // phase 2: contract this half's 128 n
      {
        const int dmu = wn2 * 16;
        const int row_a = wr2 * 32;
        __builtin_amdgcn_s_setprio(1);
#pragma unroll
        for (int kc8 = 0; kc8 < 4; ++kc8) {
          const int slot = ((kc8 << 2) + lq) ^ (lr & 7);
          const bf16x8 amu = *(const bf16x8*)&pw2_s[(dmu + lr) * 128 + (slot << 3)];
          const bf16x8 als = *(const bf16x8*)&pw2_s[(dmu + 32 + lr) * 128 + (slot << 3)];
          const bf16x8 b0 = *(const bf16x8*)&h_s[(row_a + lr) * 128 + (slot << 3)];
          const bf16x8 b1 = *(const bf16x8*)&h_s[(row_a + 16 + lr) * 128 + (slot << 3)];
          acc2[0][0] = __builtin_amdgcn_mfma_f32_16x16x32_bf16(amu, b0, acc2[0][0], 0, 0, 0);
          acc2[0][1] = __builtin_amdgcn_mfma_f32_16x16x32_bf16(als, b0, acc2[0][1], 0, 0, 0);
          acc2[1][0] = __builtin_amdgcn_mfma_f32_16x16x32_bf16(amu, b1, acc2[1][0], 0, 0, 0);
          acc2[1][1] = __builtin_amdgcn_mfma_f32_16x16x32_bf16(als, b1, acc2[1][1], 0, 0, 0);
        }
        __builtin_amdgcn_s_setprio(0);
      }
      asm volatile("s_waitcnt lgkmcnt(0)" ::: "memory");
      __builtin_amdgcn_s_barrier();   // all reads of h_s/pw2_s retired before overwrite
      if (half == 0) stage_pw2(w2p, 1);
      else if (pi < 7) stage_pw2(w2p + 16384, 0);
    }

    // per-p epilogue: accumulate iv and iv*mu into registers
    {
      const int d0 = wn2 * 16 + (lq << 2);
      const int row_a = wr2 * 32;
      const float4 b2mu = *(const float4*)(pb2 + p * 64 + d0);
      const float4 b2ls = *(const float4*)(pb2 + p * 64 + 32 + d0);
      const float wp0 = wgt[(size_t)(row0 + row_a + lr) * 16 + p];
      const float wp1 = wgt[(size_t)(row0 + row_a + 16 + lr) * 16 + p];
#pragma unroll
      for (int s = 0; s < 2; ++s) {
        const float wp = s ? wp1 : wp0;
        const float mu0 = acc2[s][0][0] + b2mu.x, ls0 = acc2[s][1][0] + b2ls.x;
        const float mu1 = acc2[s][0][1] + b2mu.y, ls1 = acc2[s][1][1] + b2ls.y;
        const float mu2 = acc2[s][0][2] + b2mu.z, ls2 = acc2[s][1][2] + b2ls.z;
        const float mu3 = acc2[s][0][3] + b2mu.w, ls3 = acc2[s][1][3] + b2ls.w;
        const float iv0 = wp * __expf(-ls0), iv1 = wp * __expf(-ls1);
        const float iv2 = wp * __expf(-ls2), iv3 = wp * __expf(-ls3);
        num[s][0] += iv0 * mu0; num[s][1] += iv1 * mu1;
        num[s][2] += iv2 * mu2; num[s][3] += iv3 * mu3;
        den[s][0] += iv0; den[s][1] += iv1;
        den[s][2] += iv2; den[s][3] += iv3;
      }
    }
  }

  // final write: fp32 partial sums for this p-group
  {
    const int d0 = wn2 * 16 + (lq << 2);
    const int row_a = wr2 * 32;
#pragma unroll
    for (int s = 0; s < 2; ++s) {
      const int row_g = row0 + row_a + s * 16 + lr;
      float* ob = outbuf + ((size_t)row_g * 2 + pg) * 64;
      *(f32x4*)(ob + d0) = num[s];
      *(f32x4*)(ob + 32 + d0) = den[s];
    }
  }
}

// ---------------- mixture finish: mean = (num0+num1)/(den0+den1) ----------------

__global__ __launch_bounds__(256) void mix_finish_k(const float* __restrict__ buf,  // [B][2][64]
                                                    float* __restrict__ mean_out) { // [B][32]
  const int gid = blockIdx.x * 256 + threadIdx.x;
  const int row = gid >> 3;
  const int a0 = (gid & 7) * 4;
  const float* rp = buf + (size_t)row * 128;
  const f32x4 n0 = *(const f32x4*)(rp + a0);
  const f32x4 d0 = *(const f32x4*)(rp + 32 + a0);
  const f32x4 n1 = *(const f32x4*)(rp + 64 + a0);
  const f32x4 d1 = *(const f32x4*)(rp + 96 + a0);
  f32x4 res;
  res[0] = (n0[0] + n1[0]) / (d0[0] + d1[0]);
  res[1] = (n0[1] + n1[1]) / (d0[1] + d1[1]);
  res[2] = (n0[2] + n1[2]) / (d0[2] + d1[2]);
  res[3] = (n0[3] + n1[3]) / (d0[3] + d1[3]);
  *(f32x4*)(mean_out + (size_t)row * 32 + a0) = res;
}

// ---------------- launcher ----------------

extern "C" void kernel_launch(void* const* d_in, const int* in_sizes, int n_in,
                              void* d_out, int out_size, void* d_ws, size_t ws_size,
                              hipStream_t stream) {
  const float* features = (const float*)d_in[0];
  const float* se_w1 = (const float*)d_in[1];
  const float* se_b1 = (const float*)d_in[2];
  const float* se_w2 = (const float*)d_in[3];
  const float* se_b2 = (const float*)d_in[4];
  const float* ge_w1 = (const float*)d_in[5];
  const float* ge_b1 = (const float*)d_in[6];
  const float* ge_w2 = (const float*)d_in[7];
  const float* ge_b2 = (const float*)d_in[8];
  const float* gt_w1 = (const float*)d_in[9];
  const float* gt_b1 = (const float*)d_in[10];
  const float* gt_w2 = (const float*)d_in[11];
  const float* gt_b2 = (const float*)d_in[12];
  const float* pse_w1 = (const float*)d_in[13];
  const float* pse_b1 = (const float*)d_in[14];
  const float* pse_w2 = (const float*)d_in[15];
  const float* pse_b2 = (const float*)d_in[16];
  const float* pw1 = (const float*)d_in[17];
  const float* pb1 = (const float*)d_in[18];
  const float* pw2 = (const float*)d_in[19];
  const float* pb2 = (const float*)d_in[20];
  const float* vf_w1 = (const float*)d_in[21];
  const float* vf_b1 = (const float*)d_in[22];
  const float* vf_w2 = (const float*)d_in[23];
  const float* vf_b2 = (const float*)d_in[24];
  (void)in_sizes; (void)n_in; (void)out_size; (void)ws_size;

  char* base = (char*)d_ws;
  size_t off = 0;
  auto alloc = [&](size_t bytes) -> char* {
    char* p = base + off;
    off += (bytes + 255) & ~(size_t)255;
    return p;
  };
  unsigned short* fbf     = (unsigned short*)alloc((size_t)NB * 640 * 2);
  unsigned short* bufA    = (unsigned short*)alloc((size_t)NB * 1024 * 2);  // s1|p1, then v1
  unsigned short* g1      = (unsigned short*)alloc((size_t)NB * 512 * 2);
  unsigned short* gate_in = (unsigned short*)alloc((size_t)NB * 512 * 2);
  unsigned short* gate_h  = (unsigned short*)alloc((size_t)NB * 256 * 2);
  unsigned short* prim    = (unsigned short*)alloc((size_t)NB * 256 * 2);
  float* wgt              = (float*)alloc((size_t)NB * 16 * 4);
  unsigned short* wcat1t  = (unsigned short*)alloc((size_t)1024 * 512 * 2);  // [se_w1t | pse_w1t]
  float* bcat1            = (float*)alloc(1024 * 4);
  unsigned short* se_w2t  = (unsigned short*)alloc(256 * 512 * 2);
  unsigned short* ge_w1t  = (unsigned short*)alloc(512 * 128 * 2);
  unsigned short* ge_w2t  = (unsigned short*)alloc(256 * 512 * 2);
  unsigned short* gt_w1t  = (unsigned short*)alloc(256 * 512 * 2);
  unsigned short* pse_w2t = (unsigned short*)alloc(256 * 512 * 2);
  unsigned short* pw1t    = (unsigned short*)alloc((size_t)16 * 256 * 256 * 2);
  unsigned short* pw2t    = (unsigned short*)alloc((size_t)16 * 64 * 256 * 2);
  unsigned short* vf_w1t  = (unsigned short*)alloc(1024 * 640 * 2);
  unsigned short* vf_w2t  = (unsigned short*)alloc(512 * 1024 * 2);

  unsigned short* se_w1t  = wcat1t;                 // rows 0-511
  unsigned short* pse_w1t = wcat1t + 512 * 512;     // rows 512-1023

  // outbuf [B][2][64] fp32 = 16MB, overlaid on bufA (dead by then).
  float* outbuf = (float*)bufA;

  float* mean_out = (float*)d_out;
  float* value_out = (float*)d_out + (size_t)NB * 32;

  fconv_k<<<dim3(10240), dim3(256), 0, stream>>>(features, fbf);
  bcat_k<<<dim3(4), dim3(256), 0, stream>>>(se_b1, pse_b1, bcat1);

  TJobs jobs;
  auto setj = [&](int i, const float* s, unsigned short* d, int K, int N, int b) {
    jobs.src[i] = s; jobs.dst[i] = d; jobs.K[i] = K; jobs.N[i] = N; jobs.batch[i] = b;
  };
  setj(0, se_w1, se_w1t, 512, 512, 1);
  setj(1, se_w2, se_w2t, 512, 256, 1);
  setj(2, ge_w1, ge_w1t, 128, 512, 1);
  setj(3, ge_w2, ge_w2t, 512, 256, 1);
  setj(4, gt_w1, gt_w1t, 512, 256, 1);
  setj(5, pse_w1, pse_w1t, 512, 512, 1);
  setj(6, pse_w2, pse_w2t, 512, 256, 1);
  setj(7, pw1, pw1t, 256, 256, 16);
  setj(8, pw2, pw2t, 256, 64, 16);
  setj(9, vf_w1, vf_w1t, 640, 1024, 1);
  setj(10, vf_w2, vf_w2t, 1024, 512, 1);
  wtrans_k<<<dim3(1024, 11), dim3(256), 0, stream>>>(jobs);

  // [s1|p1] = relu(state @ [se_w1|pse_w1] + [b|b])  N=1024: gemm2, ncl2=2
  gemm2_k<true><<<dim3(1024), dim3(256), 0, stream>>>(fbf, 640, wcat1t, bcat1, bufA, 1024, 512, 2);
  // g1 = relu(goal @ ge_w1 + b)             N=512: gemm2, K=128
  gemm2_k<true><<<dim3(512), dim3(256), 0, stream>>>(fbf + 512, 640, ge_w1t, ge_b1, g1, 512, 128, 1);
  // gate_in[:, :256] = relu(s1 @ se_w2 + b) N=256: gemm3 (A = bufA cols 0-511, lda 1024)
  gemm3_k<true><<<dim3(512), dim3(256), 0, stream>>>(bufA, 1024, se_w2t, se_b2, gate_in, 512, 512, 1);
  // gate_in[:, 256:] = relu(g1 @ ge_w2 + b) N=256: gemm3
  gemm3_k<true><<<dim3(512), dim3(256), 0, stream>>>(g1, 512, ge_w2t, ge_b2, gate_in + 256, 512, 512, 1);
  // gate_h = relu(gate_in @ gt_w1 + b)      N=256: gemm3
  gemm3_k<true><<<dim3(512), dim3(256), 0, stream>>>(gate_in, 512, gt_w1t, gt_b1, gate_h, 256, 512, 1);
  // weights = sigmoid(gate_h @ gt_w2 + b)
  gt2_k<<<dim3(2048), dim3(256), 0, stream>>>(gate_h, gt_w2, gt_b2, wgt);
  // prim = relu(p1 @ pse_w2 + b)            N=256: gemm3 (A = bufA cols 512-1023)
  gemm3_k<true><<<dim3(512), dim3(256), 0, stream>>>(bufA + 512, 1024, pse_w2t, pse_b2, prim, 256, 512, 1);
  // v1 = relu(features @ vf_w1 + b)         N=1024: gemm2 (bufA now dead -> reuse)
  gemm2_k<true><<<dim3(1024), dim3(256), 0, stream>>>(fbf, 640, vf_w1t, vf_b1, bufA, 1024, 640, 2);
  // value = relu(v1 @ vf_w2 + b) (fp32 out) N=512: gemm2
  gemm2_k<false><<<dim3(512), dim3(256), 0, stream>>>(bufA, 1024, vf_w2t, vf_b2, value_out, 512, 1024, 1);
  // mean head: 512 blocks (2/CU, all co-resident), 8 p's per block
  prim_head_k<<<dim3(256, 2), dim3(512), 0, stream>>>(prim, wgt, pw1t, pb1, pw2t, pb2, outbuf);
  // reduce the 2 p-group partials
  mix_finish_k<<<dim3(1024), dim3(256), 0, stream>>>(outbuf, mean_out);
}

// Round 17
// 419.269 us; speedup vs baseline: 1.0338x; 1.0338x over previous
//
#include <hip/hip_runtime.h>
#include <stdint.h>

#define NB 32768

typedef __bf16 bf16x8 __attribute__((ext_vector_type(8)));
typedef float f32x4 __attribute__((ext_vector_type(4)));

// native packed f32->bf16 (RNE, compiles to v_cvt_pk_bf16_f32)
__device__ __forceinline__ unsigned pack_bf2(float a, float b) {
  union { __bf16 h[2]; unsigned u; } t;
  t.h[0] = (__bf16)a; t.h[1] = (__bf16)b;
  return t.u;
}
__device__ __forceinline__ unsigned short bf16b(float f) {
  union { __bf16 h; unsigned short u; } t;
  t.h = (__bf16)f;
  return t.u;
}
__device__ __forceinline__ float bf2f(unsigned short h) {
  union { unsigned u; float f; } v; v.u = ((unsigned)h) << 16;
  return v.f;
}

// global -> LDS direct copy, 16B per lane. LDS dest is wave-uniform base + lane*16.
__device__ __forceinline__ void gld_lds16(void* lds, const void* g) {
  __builtin_amdgcn_global_load_lds(
      (__attribute__((address_space(1))) unsigned int*)(uintptr_t)g,
      (__attribute__((address_space(3))) unsigned int*)(uintptr_t)lds,
      16, 0, 0);
}

// XCD-chunk swizzle (nwg % 8 == 0): contiguous wgid chunks land on one XCD.
__device__ __forceinline__ int xcd_swz(int bid, int nwg) {
  return (bid & 7) * (nwg >> 3) + (bid >> 3);
}

// ---------------- prep kernels ----------------

__global__ __launch_bounds__(256) void fconv_k(const float* __restrict__ src,
                                               unsigned short* __restrict__ dst) {
  size_t idx = ((size_t)blockIdx.x * 256 + threadIdx.x) * 8;
  float4 a = *(const float4*)(src + idx);
  float4 b = *(const float4*)(src + idx + 4);
  uint4 o;
  o.x = pack_bf2(a.x, a.y); o.y = pack_bf2(a.z, a.w);
  o.z = pack_bf2(b.x, b.y); o.w = pack_bf2(b.z, b.w);
  *(uint4*)(dst + idx) = o;
}

// bias concat: dst[0:512]=a, dst[512:1024]=b
__global__ __launch_bounds__(256) void bcat_k(const float* __restrict__ a,
                                              const float* __restrict__ b,
                                              float* __restrict__ dst) {
  const int i = blockIdx.x * 256 + threadIdx.x;
  dst[i] = (i < 512) ? a[i] : b[i - 512];
}

struct TJobs {
  const float* src[11];
  unsigned short* dst[11];
  int K[11], N[11], batch[11];
};

// transpose fp32 [K][N] -> bf16 [N][K], batched, 32x32 tiles
__global__ __launch_bounds__(256) void wtrans_k(TJobs jobs) {
  const int job = blockIdx.y;
  const int K = jobs.K[job], N = jobs.N[job];
  const int KT = K >> 5, NT = N >> 5;
  const int ntiles = jobs.batch[job] * KT * NT;
  const int t = blockIdx.x;
  if (t >= ntiles) return;
  const int b = t / (KT * NT);
  const int rem = t - b * KT * NT;
  const int kt = rem / NT, nt = rem - kt * NT;
  const float* src = jobs.src[job] + (size_t)b * K * N;
  unsigned short* dst = jobs.dst[job] + (size_t)b * K * N;
  __shared__ float tile[32][33];
  const int i = threadIdx.x >> 5, jj = threadIdx.x & 31;
#pragma unroll
  for (int s = 0; s < 4; ++s)
    tile[i + 8 * s][jj] = src[(size_t)(kt * 32 + i + 8 * s) * N + nt * 32 + jj];
  __syncthreads();
#pragma unroll
  for (int s = 0; s < 4; ++s)
    dst[(size_t)(nt * 32 + i + 8 * s) * K + kt * 32 + jj] = bf16b(tile[jj][i + 8 * s]);
}

// ---------------- wide GEMM (N>=512): 128x256 tile, BK=32 ----------------
// 3-buffer LDS ring, 2-deep prefetch, counted vmcnt (R11-verified).

template <bool OUT_BF16>
__global__ __launch_bounds__(256, 2) void gemm2_k(const unsigned short* __restrict__ A, int lda,
                                                  const unsigned short* __restrict__ WT,
                                                  const float* __restrict__ bias,
                                                  void* __restrict__ Cout, int ldc, int K,
                                                  int ncl2) {
  __shared__ unsigned short a_s[3][128 * 32];  // [row][slot], slot = c ^ ((row>>1)&3)
  __shared__ unsigned short b_s[3][256 * 32];  // [n][slot]
  const int tid = threadIdx.x;
  const int l = tid & 63, w = tid >> 6;   // w = wn 0..3
  const int lr = l & 15, lq = l >> 4;
  const int wg = xcd_swz(blockIdx.x, gridDim.x);
  const int col0 = (wg & ((1 << ncl2) - 1)) << 8;
  const int row0 = (wg >> ncl2) << 7;
  const int wbase = tid & ~63;

  auto stage = [&](int t) {
    const int buf = t % 3;
    const int k0 = t << 5;
#pragma unroll
    for (int i = 0; i < 2; ++i) {  // A: 512 slots
      const int s = i * 256 + tid;
      const int r = s >> 2, c = s & 3;
      const int cs = c ^ ((r >> 1) & 3);
      gld_lds16(&a_s[buf][(size_t)(i * 256 + wbase) * 8],
                A + (size_t)(row0 + r) * lda + k0 + cs * 8);
    }
#pragma unroll
    for (int i = 0; i < 4; ++i) {  // B: 1024 slots
      const int s = i * 256 + tid;
      const int n = s >> 2, c = s & 3;
      const int cs = c ^ ((n >> 1) & 3);
      gld_lds16(&b_s[buf][(size_t)(i * 256 + wbase) * 8],
                WT + (size_t)(col0 + n) * K + k0 + cs * 8);
    }
  };

  f32x4 acc[8][4] = {};
  const int nt = K >> 5;
  stage(0);
  stage(1);
#pragma unroll 1
  for (int t = 0; t < nt; ++t) {
    if (t + 1 < nt) asm volatile("s_waitcnt vmcnt(6)" ::: "memory");
    else            asm volatile("s_waitcnt vmcnt(0)" ::: "memory");
    __builtin_amdgcn_s_barrier();
    if (t + 2 < nt) stage(t + 2);
    const int cur = t % 3;
    bf16x8 av[8], bv[4];
#pragma unroll
    for (int mf = 0; mf < 8; ++mf) {
      const int r = mf * 16 + lr;
      av[mf] = *(const bf16x8*)&a_s[cur][r * 32 + ((lq ^ ((r >> 1) & 3)) << 3)];
    }
#pragma unroll
    for (int nf = 0; nf < 4; ++nf) {
      const int n = w * 64 + nf * 16 + lr;
      bv[nf] = *(const bf16x8*)&b_s[cur][n * 32 + ((lq ^ ((n >> 1) & 3)) << 3)];
    }
#pragma unroll
    for (int mf = 0; mf < 8; ++mf)
#pragma unroll
      for (int nf = 0; nf < 4; ++nf)
        acc[mf][nf] = __builtin_amdgcn_mfma_f32_16x16x32_bf16(av[mf], bv[nf], acc[mf][nf], 0, 0, 0);
  }

#pragma unroll
  for (int nf = 0; nf < 4; ++nf) {
    const int gc = col0 + w * 64 + nf * 16 + lr;
    const float bb = bias[gc];
#pragma unroll
    for (int mf = 0; mf < 8; ++mf) {
      const int gr = row0 + mf * 16 + (lq << 2);
#pragma unroll
      for (int r = 0; r < 4; ++r) {
        float v = acc[mf][nf][r] + bb;
        v = fmaxf(v, 0.0f);
        if (OUT_BF16)
          ((unsigned short*)Cout)[(size_t)(gr + r) * ldc + gc] = bf16b(v);
        else
          ((float*)Cout)[(size_t)(gr + r) * ldc + gc] = v;
      }
    }
  }
}

// ---------------- dual narrow GEMM (two independent N=256 K=512 jobs) ----------------
// Blocks 0..511 -> job0, 512..1023 -> job1. K-loop byte-identical to the
// R15-verified gemm3 (3-buffer ring, counted vmcnt, 2/CU).

__global__ __launch_bounds__(256, 2) void gemm3_dual_k(
    const unsigned short* __restrict__ A0, int lda0,
    const unsigned short* __restrict__ W0, const float* __restrict__ b0,
    unsigned short* __restrict__ C0, int ldc0,
    const unsigned short* __restrict__ A1, int lda1,
    const unsigned short* __restrict__ W1, const float* __restrict__ b1,
    unsigned short* __restrict__ C1, int ldc1) {
  __shared__ unsigned short a_s[3][128 * 32];
  __shared__ unsigned short b_s[3][128 * 32];
  const int tid = threadIdx.x;
  const int l = tid & 63, w = tid >> 6;
  const int wm = w >> 1, wn = w & 1;
  const int lr = l & 15, lq = l >> 4;
  const int job = blockIdx.x >> 9;
  const unsigned short* A  = job ? A1 : A0;
  const unsigned short* WT = job ? W1 : W0;
  const float* bias        = job ? b1 : b0;
  unsigned short* Cout     = job ? C1 : C0;
  const int lda = job ? lda1 : lda0;
  const int ldc = job ? ldc1 : ldc0;
  const int wg = xcd_swz(blockIdx.x & 511, 512);
  const int col0 = (wg & 1) << 7;
  const int row0 = (wg >> 1) << 7;
  const int wbase = tid & ~63;
  const int K = 512;

  auto stage = [&](int t) {
    const int buf = t % 3;
    const int k0 = t << 5;
#pragma unroll
    for (int i = 0; i < 2; ++i) {  // A: 512 slots
      const int s = i * 256 + tid;
      const int r = s >> 2, c = s & 3;
      const int cs = c ^ ((r >> 1) & 3);
      gld_lds16(&a_s[buf][(size_t)(i * 256 + wbase) * 8],
                A + (size_t)(row0 + r) * lda + k0 + cs * 8);
    }
#pragma unroll
    for (int i = 0; i < 2; ++i) {  // B: 512 slots
      const int s = i * 256 + tid;
      const int n = s >> 2, c = s & 3;
      const int cs = c ^ ((n >> 1) & 3);
      gld_lds16(&b_s[buf][(size_t)(i * 256 + wbase) * 8],
                WT + (size_t)(col0 + n) * K + k0 + cs * 8);
    }
  };

  f32x4 acc[4][4] = {};
  const int nt = K >> 5;
  stage(0);
  stage(1);
#pragma unroll 1
  for (int t = 0; t < nt; ++t) {
    if (t + 1 < nt) asm volatile("s_waitcnt vmcnt(4)" ::: "memory");
    else            asm volatile("s_waitcnt vmcnt(0)" ::: "memory");
    __builtin_amdgcn_s_barrier();
    if (t + 2 < nt) stage(t + 2);
    const int cur = t % 3;
    bf16x8 av[4], bv[4];
#pragma unroll
    for (int mf = 0; mf < 4; ++mf) {
      const int r = wm * 64 + mf * 16 + lr;
      av[mf] = *(const bf16x8*)&a_s[cur][r * 32 + ((lq ^ ((r >> 1) & 3)) << 3)];
    }
#pragma unroll
    for (int nf = 0; nf < 4; ++nf) {
      const int n = wn * 64 + nf * 16 + lr;
      bv[nf] = *(const bf16x8*)&b_s[cur][n * 32 + ((lq ^ ((n >> 1) & 3)) << 3)];
    }
#pragma unroll
    for (int mf = 0; mf < 4; ++mf)
#pragma unroll
      for (int nf = 0; nf < 4; ++nf)
        acc[mf][nf] = __builtin_amdgcn_mfma_f32_16x16x32_bf16(av[mf], bv[nf], acc[mf][nf], 0, 0, 0);
  }

#pragma unroll
  for (int nf = 0; nf < 4; ++nf) {
    const int gc = col0 + wn * 64 + nf * 16 + lr;
    const float bb = bias[gc];
#pragma unroll
    for (int mf = 0; mf < 4; ++mf) {
      const int gr = row0 + wm * 64 + mf * 16 + (lq << 2);
#pragma unroll
      for (int r = 0; r < 4; ++r) {
        float v = acc[mf][nf][r] + bb;
        v = fmaxf(v, 0.0f);
        Cout[(size_t)(gr + r) * ldc + gc] = bf16b(v);
      }
    }
  }
}

// ---------------- gate head 2: weights = sigmoid(gate_h @ gt_w2 + gt_b2), N=16 ----------------

__global__ __launch_bounds__(256) void gt2_k(const unsigned short* __restrict__ gate_h,
                                             const float* __restrict__ w2,
                                             const float* __restrict__ b2,
                                             float* __restrict__ wgt) {
  __shared__ float w_s[256 * 16];
  __shared__ unsigned short a_s[16 * 264];
  const int tid = threadIdx.x;
  const int row0 = blockIdx.x * 16;
  for (int i = tid; i < 256 * 16; i += 256) w_s[i] = w2[i];
  for (int i = tid; i < 512; i += 256) {
    const int r = i >> 5, cg = i & 31;
    *(uint4*)&a_s[r * 264 + cg * 8] =
        *(const uint4*)(gate_h + (size_t)(row0 + r) * 256 + cg * 8);
  }
  __syncthreads();
  const int rr = tid >> 4, col = tid & 15;
  float sum = b2[col];
#pragma unroll 8
  for (int k = 0; k < 256; ++k)
    sum += bf2f(a_s[rr * 264 + k]) * w_s[k * 16 + col];
  wgt[(size_t)(row0 + rr) * 16 + col] = 1.0f / (1.0f + __expf(-sum));
}

// ---------------- primitive head: per (row-tile, p-group) block (R12 form, verified) ----------------

__global__ __launch_bounds__(512, 4) void prim_head_k(
    const unsigned short* __restrict__ prim,   // [B][256] bf16
    const float* __restrict__ wgt,             // [B][16]
    const unsigned short* __restrict__ pw1t,   // [16][256n][256k] bf16
    const float* __restrict__ pb1,             // [16][256]
    const unsigned short* __restrict__ pw2t,   // [16][64d][256k] bf16
    const float* __restrict__ pb2,             // [16][64]
    float* __restrict__ outbuf)                // [B][2][64] fp32
{
  __shared__ unsigned short prim_s[2][128 * 32];  // 2x8KB [row][kc], chunk kc^((rw>>1)&3)
  __shared__ unsigned short w1_s[2][128 * 32];    // 2x8KB [n_loc][kc], chunk kc^((n>>1)&3)
  __shared__ unsigned short h_s[128 * 128];       // 32KB  [row][n_loc], chunk g at g^(row&7)
  __shared__ unsigned short pw2_s[64 * 128];      // 16KB  [d][k_loc],  chunk g at g^(d&7)
  const int tid = threadIdx.x;
  const int l = tid & 63;
  const int w = tid >> 6;
  const int lr = l & 15, lq = l >> 4;
  const int wn2 = w & 1, wr2 = w >> 1;
  const int row0 = blockIdx.x << 7;
  const int pg = blockIdx.y;           // 0..1
  const int p0 = pg << 3;
  const int wbase = tid & ~63;

  auto stage_ab = [&](const unsigned short* w1p_, int t) {
    const int buf = t & 1;
    const int k0 = (t & 7) << 5;
    const int nb2 = (t >> 3) << 7;
    const int rw = tid >> 2, kc = tid & 3;
    const int kcs = kc ^ ((rw >> 1) & 3);
    gld_lds16(&prim_s[buf][(size_t)wbase * 8],
              prim + (size_t)(row0 + rw) * 256 + k0 + kcs * 8);
    gld_lds16(&w1_s[buf][(size_t)wbase * 8],
              w1p_ + (size_t)(nb2 + rw) * 256 + k0 + kcs * 8);
  };
  auto stage_pw2 = [&](const unsigned short* w2p_, int half) {
    const int nbase = half << 7;
#pragma unroll
    for (int i = 0; i < 2; ++i) {
      const int c = i * 512 + tid;
      const int d = c >> 4, kc = c & 15;
      gld_lds16(&pw2_s[(size_t)(i * 512 + wbase) * 8],
                w2p_ + (size_t)d * 256 + nbase + ((kc ^ (d & 7)) << 3));
    }
  };

  stage_ab(pw1t + (size_t)p0 * 65536, 0);
  stage_pw2(pw2t + (size_t)p0 * 16384, 0);

  f32x4 num[2] = {}, den[2] = {};

#pragma unroll 1
  for (int pi = 0; pi < 8; ++pi) {
    const int p = p0 + pi;
    const unsigned short* w1p = pw1t + (size_t)p * 65536;
    const unsigned short* w2p = pw2t + (size_t)p * 16384;

    f32x4 acc2[2][2] = {};

    for (int half = 0; half < 2; ++half) {
      float4 pb1v[4];
#pragma unroll
      for (int nf = 0; nf < 4; ++nf)
        pb1v[nf] = *(const float4*)(pb1 + p * 256 + (half << 7) + wn2 * 64 + nf * 16 + (lq << 2));

      f32x4 acc1[4][2] = {};
#pragma unroll 1
      for (int ks = 0; ks < 8; ++ks) {
        const int t = (half << 3) + ks;
        const int cur = t & 1;
        asm volatile("s_waitcnt vmcnt(0)" ::: "memory");
        __builtin_amdgcn_s_barrier();
        if (t < 15) stage_ab(w1p, t + 1);
        else if (pi < 7) stage_ab(w1p + 65536, 0);
        bf16x8 av[4], bv[2];
#pragma unroll
        for (int nf = 0; nf < 4; ++nf) {
          const int n = wn2 * 64 + nf * 16 + lr;
          av[nf] = *(const bf16x8*)&w1_s[cur][n * 32 + ((lq ^ ((n >> 1) & 3)) << 3)];
        }
#pragma unroll
        for (int rf = 0; rf < 2; ++rf) {
          const int r = wr2 * 32 + rf * 16 + lr;
          bv[rf] = *(const bf16x8*)&prim_s[cur][r * 32 + ((lq ^ ((r >> 1) & 3)) << 3)];
        }
#pragma unroll
        for (int nf = 0; nf < 4; ++nf)
#pragma unroll
          for (int rf = 0; rf < 2; ++rf)
            acc1[nf][rf] = __builtin_amdgcn_mfma_f32_16x16x32_bf16(av[nf], bv[rf], acc1[nf][rf], 0, 0, 0);
      }

      // h write (ds_write); visible via lgkmcnt only (global stages stay in flight)
#pragma unroll
      for (int nf = 0; nf < 4; ++nf) {
        const int n0 = wn2 * 64 + nf * 16 + (lq << 2);
        const float4 bb = pb1v[nf];
#pragma unroll
        for (int rf = 0; rf < 2; ++rf) {
          const int row = wr2 * 32 + rf * 16 + lr;
          uint2 pk;
          pk.x = pack_bf2(fmaxf(acc1[nf][rf][0] + bb.x, 0.0f),
                          fmaxf(acc1[nf][rf][1] + bb.y, 0.0f));
          pk.y = pack_bf2(fmaxf(acc1[nf][rf][2] + bb.z, 0.0f),
                          fmaxf(acc1[nf][rf][3] + bb.w, 0.0f));
          *(uint2*)&h_s[row * 128 + (((n0 >> 3) ^ (row & 7)) << 3) + (n0 & 7)] = pk;
        }
      }
      asm volatile("s_waitcnt lgkmcnt(0)" ::: "memory");
      __builtin_amdgcn_s_barrier();

      // phase 2: contract this half's 128 n
      {
        const int dmu = wn2 * 16;
        const int row_a = wr2 * 32;
#pragma unroll
        for (int kc8 = 0; kc8 < 4; ++kc8) {
          const int slot = ((kc8 << 2) + lq) ^ (lr & 7);
          const bf16x8 amu = *(const bf16x8*)&pw2_s[(dmu + lr) * 128 + (slot << 3)];
          const bf16x8 als = *(const bf16x8*)&pw2_s[(dmu + 32 + lr) * 128 + (slot << 3)];
          const bf16x8 b0 = *(const bf16x8*)&h_s[(row_a + lr) * 128 + (slot << 3)];
          const bf16x8 b1 = *(const bf16x8*)&h_s[(row_a + 16 + lr) * 128 + (slot << 3)];
          acc2[0][0] = __builtin_amdgcn_mfma_f32_16x16x32_bf16(amu, b0, acc2[0][0], 0, 0, 0);
          acc2[0][1] = __builtin_amdgcn_mfma_f32_16x16x32_bf16(als, b0, acc2[0][1], 0, 0, 0);
          acc2[1][0] = __builtin_amdgcn_mfma_f32_16x16x32_bf16(amu, b1, acc2[1][0], 0, 0, 0);
          acc2[1][1] = __builtin_amdgcn_mfma_f32_16x16x32_bf16(als, b1, acc2[1][1], 0, 0, 0);
        }
      }
      asm volatile("s_waitcnt lgkmcnt(0)" ::: "memory");
      __builtin_amdgcn_s_barrier();   // all reads of h_s/pw2_s retired before overwrite
      if (half == 0) stage_pw2(w2p, 1);
      else if (pi < 7) stage_pw2(w2p + 16384, 0);
    }

    // per-p epilogue: accumulate iv and iv*mu into registers
    {
      const int d0 = wn2 * 16 + (lq << 2);
      const int row_a = wr2 * 32;
      const float4 b2mu = *(const float4*)(pb2 + p * 64 + d0);
      const float4 b2ls = *(const float4*)(pb2 + p * 64 + 32 + d0);
      const float wp0 = wgt[(size_t)(row0 + row_a + lr) * 16 + p];
      const float wp1 = wgt[(size_t)(row0 + row_a + 16 + lr) * 16 + p];
#pragma unroll
      for (int s = 0; s < 2; ++s) {
        const float wp = s ? wp1 : wp0;
        const float mu0 = acc2[s][0][0] + b2mu.x, ls0 = acc2[s][1][0] + b2ls.x;
        const float mu1 = acc2[s][0][1] + b2mu.y, ls1 = acc2[s][1][1] + b2ls.y;
        const float mu2 = acc2[s][0][2] + b2mu.z, ls2 = acc2[s][1][2] + b2ls.z;
        const float mu3 = acc2[s][0][3] + b2mu.w, ls3 = acc2[s][1][3] + b2ls.w;
        const float iv0 = wp * __expf(-ls0), iv1 = wp * __expf(-ls1);
        const float iv2 = wp * __expf(-ls2), iv3 = wp * __expf(-ls3);
        num[s][0] += iv0 * mu0; num[s][1] += iv1 * mu1;
        num[s][2] += iv2 * mu2; num[s][3] += iv3 * mu3;
        den[s][0] += iv0; den[s][1] += iv1;
        den[s][2] += iv2; den[s][3] += iv3;
      }
    }
  }

  // final write: fp32 partial sums for this p-group
  {
    const int d0 = wn2 * 16 + (lq << 2);
    const int row_a = wr2 * 32;
#pragma unroll
    for (int s = 0; s < 2; ++s) {
      const int row_g = row0 + row_a + s * 16 + lr;
      float* ob = outbuf + ((size_t)row_g * 2 + pg) * 64;
      *(f32x4*)(ob + d0) = num[s];
      *(f32x4*)(ob + 32 + d0) = den[s];
    }
  }
}

// ---------------- mixture finish: mean = (num0+num1)/(den0+den1) ----------------

__global__ __launch_bounds__(256) void mix_finish_k(const float* __restrict__ buf,  // [B][2][64]
                                                    float* __restrict__ mean_out) { // [B][32]
  const int gid = blockIdx.x * 256 + threadIdx.x;
  const int row = gid >> 3;
  const int a0 = (gid & 7) * 4;
  const float* rp = buf + (size_t)row * 128;
  const f32x4 n0 = *(const f32x4*)(rp + a0);
  const f32x4 d0 = *(const f32x4*)(rp + 32 + a0);
  const f32x4 n1 = *(const f32x4*)(rp + 64 + a0);
  const f32x4 d1 = *(const f32x4*)(rp + 96 + a0);
  f32x4 res;
  res[0] = (n0[0] + n1[0]) / (d0[0] + d1[0]);
  res[1] = (n0[1] + n1[1]) / (d0[1] + d1[1]);
  res[2] = (n0[2] + n1[2]) / (d0[2] + d1[2]);
  res[3] = (n0[3] + n1[3]) / (d0[3] + d1[3]);
  *(f32x4*)(mean_out + (size_t)row * 32 + a0) = res;
}

// ---------------- launcher ----------------

extern "C" void kernel_launch(void* const* d_in, const int* in_sizes, int n_in,
                              void* d_out, int out_size, void* d_ws, size_t ws_size,
                              hipStream_t stream) {
  const float* features = (const float*)d_in[0];
  const float* se_w1 = (const float*)d_in[1];
  const float* se_b1 = (const float*)d_in[2];
  const float* se_w2 = (const float*)d_in[3];
  const float* se_b2 = (const float*)d_in[4];
  const float* ge_w1 = (const float*)d_in[5];
  const float* ge_b1 = (const float*)d_in[6];
  const float* ge_w2 = (const float*)d_in[7];
  const float* ge_b2 = (const float*)d_in[8];
  const float* gt_w1 = (const float*)d_in[9];
  const float* gt_b1 = (const float*)d_in[10];
  const float* gt_w2 = (const float*)d_in[11];
  const float* gt_b2 = (const float*)d_in[12];
  const float* pse_w1 = (const float*)d_in[13];
  const float* pse_b1 = (const float*)d_in[14];
  const float* pse_w2 = (const float*)d_in[15];
  const float* pse_b2 = (const float*)d_in[16];
  const float* pw1 = (const float*)d_in[17];
  const float* pb1 = (const float*)d_in[18];
  const float* pw2 = (const float*)d_in[19];
  const float* pb2 = (const float*)d_in[20];
  const float* vf_w1 = (const float*)d_in[21];
  const float* vf_b1 = (const float*)d_in[22];
  const float* vf_w2 = (const float*)d_in[23];
  const float* vf_b2 = (const float*)d_in[24];
  (void)in_sizes; (void)n_in; (void)out_size; (void)ws_size;

  char* base = (char*)d_ws;
  size_t off = 0;
  auto alloc = [&](size_t bytes) -> char* {
    char* p = base + off;
    off += (bytes + 255) & ~(size_t)255;
    return p;
  };
  unsigned short* fbf     = (unsigned short*)alloc((size_t)NB * 640 * 2);
  unsigned short* bufA    = (unsigned short*)alloc((size_t)NB * 1024 * 2);  // s1|p1, then v1
  unsigned short* g1      = (unsigned short*)alloc((size_t)NB * 512 * 2);
  unsigned short* gate_in = (unsigned short*)alloc((size_t)NB * 512 * 2);
  unsigned short* gate_h  = (unsigned short*)alloc((size_t)NB * 256 * 2);
  unsigned short* prim    = (unsigned short*)alloc((size_t)NB * 256 * 2);
  float* wgt              = (float*)alloc((size_t)NB * 16 * 4);
  unsigned short* wcat1t  = (unsigned short*)alloc((size_t)1024 * 512 * 2);  // [se_w1t | pse_w1t]
  float* bcat1            = (float*)alloc(1024 * 4);
  unsigned short* se_w2t  = (unsigned short*)alloc(256 * 512 * 2);
  unsigned short* ge_w1t  = (unsigned short*)alloc(512 * 128 * 2);
  unsigned short* ge_w2t  = (unsigned short*)alloc(256 * 512 * 2);
  unsigned short* gt_w1t  = (unsigned short*)alloc(256 * 512 * 2);
  unsigned short* pse_w2t = (unsigned short*)alloc(256 * 512 * 2);
  unsigned short* pw1t    = (unsigned short*)alloc((size_t)16 * 256 * 256 * 2);
  unsigned short* pw2t    = (unsigned short*)alloc((size_t)16 * 64 * 256 * 2);
  unsigned short* vf_w1t  = (unsigned short*)alloc(1024 * 640 * 2);
  unsigned short* vf_w2t  = (unsigned short*)alloc(512 * 1024 * 2);

  unsigned short* se_w1t  = wcat1t;                 // rows 0-511
  unsigned short* pse_w1t = wcat1t + 512 * 512;     // rows 512-1023

  // outbuf [B][2][64] fp32 = 16MB, overlaid on bufA (dead by then).
  float* outbuf = (float*)bufA;

  float* mean_out = (float*)d_out;
  float* value_out = (float*)d_out + (size_t)NB * 32;

  fconv_k<<<dim3(10240), dim3(256), 0, stream>>>(features, fbf);
  bcat_k<<<dim3(4), dim3(256), 0, stream>>>(se_b1, pse_b1, bcat1);

  TJobs jobs;
  auto setj = [&](int i, const float* s, unsigned short* d, int K, int N, int b) {
    jobs.src[i] = s; jobs.dst[i] = d; jobs.K[i] = K; jobs.N[i] = N; jobs.batch[i] = b;
  };
  setj(0, se_w1, se_w1t, 512, 512, 1);
  setj(1, se_w2, se_w2t, 512, 256, 1);
  setj(2, ge_w1, ge_w1t, 128, 512, 1);
  setj(3, ge_w2, ge_w2t, 512, 256, 1);
  setj(4, gt_w1, gt_w1t, 512, 256, 1);
  setj(5, pse_w1, pse_w1t, 512, 512, 1);
  setj(6, pse_w2, pse_w2t, 512, 256, 1);
  setj(7, pw1, pw1t, 256, 256, 16);
  setj(8, pw2, pw2t, 256, 64, 16);
  setj(9, vf_w1, vf_w1t, 640, 1024, 1);
  setj(10, vf_w2, vf_w2t, 1024, 512, 1);
  wtrans_k<<<dim3(1024, 11), dim3(256), 0, stream>>>(jobs);

  // [s1|p1] = relu(state @ [se_w1|pse_w1] + [b|b])  N=1024: gemm2, ncl2=2
  gemm2_k<true><<<dim3(1024), dim3(256), 0, stream>>>(fbf, 640, wcat1t, bcat1, bufA, 1024, 512, 2);
  // g1 = relu(goal @ ge_w1 + b)             N=512: gemm2, K=128
  gemm2_k<true><<<dim3(512), dim3(256), 0, stream>>>(fbf + 512, 640, ge_w1t, ge_b1, g1, 512, 128, 1);
  // DUAL: gate_in[:,0:256] = relu(s1 @ se_w2 + b)  ||  gate_in[:,256:512] = relu(g1 @ ge_w2 + b)
  gemm3_dual_k<<<dim3(1024), dim3(256), 0, stream>>>(
      bufA, 1024, se_w2t, se_b2, gate_in, 512,
      g1, 512, ge_w2t, ge_b2, gate_in + 256, 512);
  // DUAL: gate_h = relu(gate_in @ gt_w1 + b)  ||  prim = relu(p1 @ pse_w2 + b)
  gemm3_dual_k<<<dim3(1024), dim3(256), 0, stream>>>(
      gate_in, 512, gt_w1t, gt_b1, gate_h, 256,
      bufA + 512, 1024, pse_w2t, pse_b2, prim, 256);
  // weights = sigmoid(gate_h @ gt_w2 + b)
  gt2_k<<<dim3(2048), dim3(256), 0, stream>>>(gate_h, gt_w2, gt_b2, wgt);
  // v1 = relu(features @ vf_w1 + b)         N=1024: gemm2 (bufA now dead -> reuse)
  gemm2_k<true><<<dim3(1024), dim3(256), 0, stream>>>(fbf, 640, vf_w1t, vf_b1, bufA, 1024, 640, 2);
  // value = relu(v1 @ vf_w2 + b) (fp32 out) N=512: gemm2
  gemm2_k<false><<<dim3(512), dim3(256), 0, stream>>>(bufA, 1024, vf_w2t, vf_b2, value_out, 512, 1024, 1);
  // mean head: 512 blocks (2/CU, all co-resident), 8 p's per block
  prim_head_k<<<dim3(256, 2), dim3(512), 0, stream>>>(prim, wgt, pw1t, pb1, pw2t, pb2, outbuf);
  // reduce the 2 p-group partials
  mix_finish_k<<<dim3(1024), dim3(256), 0, stream>>>(outbuf, mean_out);
}

// Round 18
// 407.519 us; speedup vs baseline: 1.0636x; 1.0288x over previous
//
#include <hip/hip_runtime.h>
#include <stdint.h>

#define NB 32768

typedef __bf16 bf16x8 __attribute__((ext_vector_type(8)));
typedef float f32x4 __attribute__((ext_vector_type(4)));

// native packed f32->bf16 (RNE, compiles to v_cvt_pk_bf16_f32)
__device__ __forceinline__ unsigned pack_bf2(float a, float b) {
  union { __bf16 h[2]; unsigned u; } t;
  t.h[0] = (__bf16)a; t.h[1] = (__bf16)b;
  return t.u;
}
__device__ __forceinline__ unsigned short bf16b(float f) {
  union { __bf16 h; unsigned short u; } t;
  t.h = (__bf16)f;
  return t.u;
}
__device__ __forceinline__ float bf2f(unsigned short h) {
  union { unsigned u; float f; } v; v.u = ((unsigned)h) << 16;
  return v.f;
}

// global -> LDS direct copy, 16B per lane. LDS dest is wave-uniform base + lane*16.
__device__ __forceinline__ void gld_lds16(void* lds, const void* g) {
  __builtin_amdgcn_global_load_lds(
      (__attribute__((address_space(1))) unsigned int*)(uintptr_t)g,
      (__attribute__((address_space(3))) unsigned int*)(uintptr_t)lds,
      16, 0, 0);
}

// XCD-chunk swizzle (nwg % 8 == 0): contiguous wgid chunks land on one XCD.
__device__ __forceinline__ int xcd_swz(int bid, int nwg) {
  return (bid & 7) * (nwg >> 3) + (bid >> 3);
}

// ---------------- prep kernels ----------------

__global__ __launch_bounds__(256) void fconv_k(const float* __restrict__ src,
                                               unsigned short* __restrict__ dst) {
  size_t idx = ((size_t)blockIdx.x * 256 + threadIdx.x) * 8;
  float4 a = *(const float4*)(src + idx);
  float4 b = *(const float4*)(src + idx + 4);
  uint4 o;
  o.x = pack_bf2(a.x, a.y); o.y = pack_bf2(a.z, a.w);
  o.z = pack_bf2(b.x, b.y); o.w = pack_bf2(b.z, b.w);
  *(uint4*)(dst + idx) = o;
}

// bias concat: dst[0:512]=a, dst[512:1024]=b
__global__ __launch_bounds__(256) void bcat_k(const float* __restrict__ a,
                                              const float* __restrict__ b,
                                              float* __restrict__ dst) {
  const int i = blockIdx.x * 256 + threadIdx.x;
  dst[i] = (i < 512) ? a[i] : b[i - 512];
}

struct TJobs {
  const float* src[11];
  unsigned short* dst[11];
  int K[11], N[11], batch[11];
};

// transpose fp32 [K][N] -> bf16 [N][K], batched, 32x32 tiles
__global__ __launch_bounds__(256) void wtrans_k(TJobs jobs) {
  const int job = blockIdx.y;
  const int K = jobs.K[job], N = jobs.N[job];
  const int KT = K >> 5, NT = N >> 5;
  const int ntiles = jobs.batch[job] * KT * NT;
  const int t = blockIdx.x;
  if (t >= ntiles) return;
  const int b = t / (KT * NT);
  const int rem = t - b * KT * NT;
  const int kt = rem / NT, nt = rem - kt * NT;
  const float* src = jobs.src[job] + (size_t)b * K * N;
  unsigned short* dst = jobs.dst[job] + (size_t)b * K * N;
  __shared__ float tile[32][33];
  const int i = threadIdx.x >> 5, jj = threadIdx.x & 31;
#pragma unroll
  for (int s = 0; s < 4; ++s)
    tile[i + 8 * s][jj] = src[(size_t)(kt * 32 + i + 8 * s) * N + nt * 32 + jj];
  __syncthreads();
#pragma unroll
  for (int s = 0; s < 4; ++s)
    dst[(size_t)(nt * 32 + i + 8 * s) * K + kt * 32 + jj] = bf16b(tile[jj][i + 8 * s]);
}

// ---------------- wide GEMM (N>=512): 128x256 tile, BK=32 ----------------
// 3-buffer LDS ring, 2-deep prefetch, counted vmcnt (R11-verified).
// Body shared between the single and dual entry points.

template <bool OUT_BF16>
__device__ __forceinline__ void gemm2_body(const unsigned short* __restrict__ A, int lda,
                                           const unsigned short* __restrict__ WT,
                                           const float* __restrict__ bias,
                                           void* __restrict__ Cout, int ldc, int K,
                                           int ncl2, int bid, int nwg,
                                           unsigned short (*a_s)[128 * 32],
                                           unsigned short (*b_s)[256 * 32]) {
  const int tid = threadIdx.x;
  const int l = tid & 63, w = tid >> 6;   // w = wn 0..3
  const int lr = l & 15, lq = l >> 4;
  const int wg = xcd_swz(bid, nwg);
  const int col0 = (wg & ((1 << ncl2) - 1)) << 8;
  const int row0 = (wg >> ncl2) << 7;
  const int wbase = tid & ~63;

  auto stage = [&](int t) {
    const int buf = t % 3;
    const int k0 = t << 5;
#pragma unroll
    for (int i = 0; i < 2; ++i) {  // A: 512 slots
      const int s = i * 256 + tid;
      const int r = s >> 2, c = s & 3;
      const int cs = c ^ ((r >> 1) & 3);
      gld_lds16(&a_s[buf][(size_t)(i * 256 + wbase) * 8],
                A + (size_t)(row0 + r) * lda + k0 + cs * 8);
    }
#pragma unroll
    for (int i = 0; i < 4; ++i) {  // B: 1024 slots
      const int s = i * 256 + tid;
      const int n = s >> 2, c = s & 3;
      const int cs = c ^ ((n >> 1) & 3);
      gld_lds16(&b_s[buf][(size_t)(i * 256 + wbase) * 8],
                WT + (size_t)(col0 + n) * K + k0 + cs * 8);
    }
  };

  f32x4 acc[8][4] = {};
  const int nt = K >> 5;
  stage(0);
  stage(1);
#pragma unroll 1
  for (int t = 0; t < nt; ++t) {
    if (t + 1 < nt) asm volatile("s_waitcnt vmcnt(6)" ::: "memory");
    else            asm volatile("s_waitcnt vmcnt(0)" ::: "memory");
    __builtin_amdgcn_s_barrier();
    if (t + 2 < nt) stage(t + 2);
    const int cur = t % 3;
    bf16x8 av[8], bv[4];
#pragma unroll
    for (int mf = 0; mf < 8; ++mf) {
      const int r = mf * 16 + lr;
      av[mf] = *(const bf16x8*)&a_s[cur][r * 32 + ((lq ^ ((r >> 1) & 3)) << 3)];
    }
#pragma unroll
    for (int nf = 0; nf < 4; ++nf) {
      const int n = w * 64 + nf * 16 + lr;
      bv[nf] = *(const bf16x8*)&b_s[cur][n * 32 + ((lq ^ ((n >> 1) & 3)) << 3)];
    }
#pragma unroll
    for (int mf = 0; mf < 8; ++mf)
#pragma unroll
      for (int nf = 0; nf < 4; ++nf)
        acc[mf][nf] = __builtin_amdgcn_mfma_f32_16x16x32_bf16(av[mf], bv[nf], acc[mf][nf], 0, 0, 0);
  }

#pragma unroll
  for (int nf = 0; nf < 4; ++nf) {
    const int gc = col0 + w * 64 + nf * 16 + lr;
    const float bb = bias[gc];
#pragma unroll
    for (int mf = 0; mf < 8; ++mf) {
      const int gr = row0 + mf * 16 + (lq << 2);
#pragma unroll
      for (int r = 0; r < 4; ++r) {
        float v = acc[mf][nf][r] + bb;
        v = fmaxf(v, 0.0f);
        if (OUT_BF16)
          ((unsigned short*)Cout)[(size_t)(gr + r) * ldc + gc] = bf16b(v);
        else
          ((float*)Cout)[(size_t)(gr + r) * ldc + gc] = v;
      }
    }
  }
}

template <bool OUT_BF16>
__global__ __launch_bounds__(256, 2) void gemm2_k(const unsigned short* __restrict__ A, int lda,
                                                  const unsigned short* __restrict__ WT,
                                                  const float* __restrict__ bias,
                                                  void* __restrict__ Cout, int ldc, int K,
                                                  int ncl2) {
  __shared__ unsigned short a_s[3][128 * 32];
  __shared__ unsigned short b_s[3][256 * 32];
  gemm2_body<OUT_BF16>(A, lda, WT, bias, Cout, ldc, K, ncl2,
                       blockIdx.x, gridDim.x, a_s, b_s);
}

// dual wide GEMM: job0 = blocks [0, nwg0), job1 = blocks [nwg0, nwg0+nwg1)
__global__ __launch_bounds__(256, 2) void gemm2_dual_k(
    const unsigned short* __restrict__ A0, int lda0,
    const unsigned short* __restrict__ W0, const float* __restrict__ b0,
    unsigned short* __restrict__ C0, int ldc0, int K0, int ncl20, int nwg0,
    const unsigned short* __restrict__ A1, int lda1,
    const unsigned short* __restrict__ W1, const float* __restrict__ b1,
    unsigned short* __restrict__ C1, int ldc1, int K1, int ncl21, int nwg1) {
  __shared__ unsigned short a_s[3][128 * 32];
  __shared__ unsigned short b_s[3][256 * 32];
  if ((int)blockIdx.x < nwg0)
    gemm2_body<true>(A0, lda0, W0, b0, C0, ldc0, K0, ncl20,
                     blockIdx.x, nwg0, a_s, b_s);
  else
    gemm2_body<true>(A1, lda1, W1, b1, C1, ldc1, K1, ncl21,
                     blockIdx.x - nwg0, nwg1, a_s, b_s);
}

// ---------------- dual narrow GEMM (two independent N=256 K=512 jobs) ----------------

__global__ __launch_bounds__(256, 2) void gemm3_dual_k(
    const unsigned short* __restrict__ A0, int lda0,
    const unsigned short* __restrict__ W0, const float* __restrict__ b0,
    unsigned short* __restrict__ C0, int ldc0,
    const unsigned short* __restrict__ A1, int lda1,
    const unsigned short* __restrict__ W1, const float* __restrict__ b1,
    unsigned short* __restrict__ C1, int ldc1) {
  __shared__ unsigned short a_s[3][128 * 32];
  __shared__ unsigned short b_s[3][128 * 32];
  const int tid = threadIdx.x;
  const int l = tid & 63, w = tid >> 6;
  const int wm = w >> 1, wn = w & 1;
  const int lr = l & 15, lq = l >> 4;
  const int job = blockIdx.x >> 9;
  const unsigned short* A  = job ? A1 : A0;
  const unsigned short* WT = job ? W1 : W0;
  const float* bias        = job ? b1 : b0;
  unsigned short* Cout     = job ? C1 : C0;
  const int lda = job ? lda1 : lda0;
  const int ldc = job ? ldc1 : ldc0;
  const int wg = xcd_swz(blockIdx.x & 511, 512);
  const int col0 = (wg & 1) << 7;
  const int row0 = (wg >> 1) << 7;
  const int wbase = tid & ~63;
  const int K = 512;

  auto stage = [&](int t) {
    const int buf = t % 3;
    const int k0 = t << 5;
#pragma unroll
    for (int i = 0; i < 2; ++i) {  // A: 512 slots
      const int s = i * 256 + tid;
      const int r = s >> 2, c = s & 3;
      const int cs = c ^ ((r >> 1) & 3);
      gld_lds16(&a_s[buf][(size_t)(i * 256 + wbase) * 8],
                A + (size_t)(row0 + r) * lda + k0 + cs * 8);
    }
#pragma unroll
    for (int i = 0; i < 2; ++i) {  // B: 512 slots
      const int s = i * 256 + tid;
      const int n = s >> 2, c = s & 3;
      const int cs = c ^ ((n >> 1) & 3);
      gld_lds16(&b_s[buf][(size_t)(i * 256 + wbase) * 8],
                WT + (size_t)(col0 + n) * K + k0 + cs * 8);
    }
  };

  f32x4 acc[4][4] = {};
  const int nt = K >> 5;
  stage(0);
  stage(1);
#pragma unroll 1
  for (int t = 0; t < nt; ++t) {
    if (t + 1 < nt) asm volatile("s_waitcnt vmcnt(4)" ::: "memory");
    else            asm volatile("s_waitcnt vmcnt(0)" ::: "memory");
    __builtin_amdgcn_s_barrier();
    if (t + 2 < nt) stage(t + 2);
    const int cur = t % 3;
    bf16x8 av[4], bv[4];
#pragma unroll
    for (int mf = 0; mf < 4; ++mf) {
      const int r = wm * 64 + mf * 16 + lr;
      av[mf] = *(const bf16x8*)&a_s[cur][r * 32 + ((lq ^ ((r >> 1) & 3)) << 3)];
    }
#pragma unroll
    for (int nf = 0; nf < 4; ++nf) {
      const int n = wn * 64 + nf * 16 + lr;
      bv[nf] = *(const bf16x8*)&b_s[cur][n * 32 + ((lq ^ ((n >> 1) & 3)) << 3)];
    }
#pragma unroll
    for (int mf = 0; mf < 4; ++mf)
#pragma unroll
      for (int nf = 0; nf < 4; ++nf)
        acc[mf][nf] = __builtin_amdgcn_mfma_f32_16x16x32_bf16(av[mf], bv[nf], acc[mf][nf], 0, 0, 0);
  }

#pragma unroll
  for (int nf = 0; nf < 4; ++nf) {
    const int gc = col0 + wn * 64 + nf * 16 + lr;
    const float bb = bias[gc];
#pragma unroll
    for (int mf = 0; mf < 4; ++mf) {
      const int gr = row0 + wm * 64 + mf * 16 + (lq << 2);
#pragma unroll
      for (int r = 0; r < 4; ++r) {
        float v = acc[mf][nf][r] + bb;
        v = fmaxf(v, 0.0f);
        Cout[(size_t)(gr + r) * ldc + gc] = bf16b(v);
      }
    }
  }
}

// ---------------- gate head 2: weights = sigmoid(gate_h @ gt_w2 + gt_b2), N=16 ----------------

__global__ __launch_bounds__(256) void gt2_k(const unsigned short* __restrict__ gate_h,
                                             const float* __restrict__ w2,
                                             const float* __restrict__ b2,
                                             float* __restrict__ wgt) {
  __shared__ float w_s[256 * 16];
  __shared__ unsigned short a_s[16 * 264];
  const int tid = threadIdx.x;
  const int row0 = blockIdx.x * 16;
  for (int i = tid; i < 256 * 16; i += 256) w_s[i] = w2[i];
  for (int i = tid; i < 512; i += 256) {
    const int r = i >> 5, cg = i & 31;
    *(uint4*)&a_s[r * 264 + cg * 8] =
        *(const uint4*)(gate_h + (size_t)(row0 + r) * 256 + cg * 8);
  }
  __syncthreads();
  const int rr = tid >> 4, col = tid & 15;
  float sum = b2[col];
#pragma unroll 8
  for (int k = 0; k < 256; ++k)
    sum += bf2f(a_s[rr * 264 + k]) * w_s[k * 16 + col];
  wgt[(size_t)(row0 + rr) * 16 + col] = 1.0f / (1.0f + __expf(-sum));
}

// ---------------- primitive head: per (row-tile, p-group) block (R12 form, verified) ----------------

__global__ __launch_bounds__(512, 4) void prim_head_k(
    const unsigned short* __restrict__ prim,   // [B][256] bf16
    const float* __restrict__ wgt,             // [B][16]
    const unsigned short* __restrict__ pw1t,   // [16][256n][256k] bf16
    const float* __restrict__ pb1,             // [16][256]
    const unsigned short* __restrict__ pw2t,   // [16][64d][256k] bf16
    const float* __restrict__ pb2,             // [16][64]
    float* __restrict__ outbuf)                // [B][2][64] fp32
{
  __shared__ unsigned short prim_s[2][128 * 32];  // 2x8KB [row][kc], chunk kc^((rw>>1)&3)
  __shared__ unsigned short w1_s[2][128 * 32];    // 2x8KB [n_loc][kc], chunk kc^((n>>1)&3)
  __shared__ unsigned short h_s[128 * 128];       // 32KB  [row][n_loc], chunk g at g^(row&7)
  __shared__ unsigned short pw2_s[64 * 128];      // 16KB  [d][k_loc],  chunk g at g^(d&7)
  const int tid = threadIdx.x;
  const int l = tid & 63;
  const int w = tid >> 6;
  const int lr = l & 15, lq = l >> 4;
  const int wn2 = w & 1, wr2 = w >> 1;
  const int row0 = blockIdx.x << 7;
  const int pg = blockIdx.y;           // 0..1
  const int p0 = pg << 3;
  const int wbase = tid & ~63;

  auto stage_ab = [&](const unsigned short* w1p_, int t) {
    const int buf = t & 1;
    const int k0 = (t & 7) << 5;
    const int nb2 = (t >> 3) << 7;
    const int rw = tid >> 2, kc = tid & 3;
    const int kcs = kc ^ ((rw >> 1) & 3);
    gld_lds16(&prim_s[buf][(size_t)wbase * 8],
              prim + (size_t)(row0 + rw) * 256 + k0 + kcs * 8);
    gld_lds16(&w1_s[buf][(size_t)wbase * 8],
              w1p_ + (size_t)(nb2 + rw) * 256 + k0 + kcs * 8);
  };
  auto stage_pw2 = [&](const unsigned short* w2p_, int half) {
    const int nbase = half << 7;
#pragma unroll
    for (int i = 0; i < 2; ++i) {
      const int c = i * 512 + tid;
      const int d = c >> 4, kc = c & 15;
      gld_lds16(&pw2_s[(size_t)(i * 512 + wbase) * 8],
                w2p_ + (size_t)d * 256 + nbase + ((kc ^ (d & 7)) << 3));
    }
  };

  stage_ab(pw1t + (size_t)p0 * 65536, 0);
  stage_pw2(pw2t + (size_t)p0 * 16384, 0);

  f32x4 num[2] = {}, den[2] = {};

#pragma unroll 1
  for (int pi = 0; pi < 8; ++pi) {
    const int p = p0 + pi;
    const unsigned short* w1p = pw1t + (size_t)p * 65536;
    const unsigned short* w2p = pw2t + (size_t)p * 16384;

    f32x4 acc2[2][2] = {};

    for (int half = 0; half < 2; ++half) {
      float4 pb1v[4];
#pragma unroll
      for (int nf = 0; nf < 4; ++nf)
        pb1v[nf] = *(const float4*)(pb1 + p * 256 + (half << 7) + wn2 * 64 + nf * 16 + (lq << 2));

      f32x4 acc1[4][2] = {};
#pragma unroll 1
      for (int ks = 0; ks < 8; ++ks) {
        const int t = (half << 3) + ks;
        const int cur = t & 1;
        asm volatile("s_waitcnt vmcnt(0)" ::: "memory");
        __builtin_amdgcn_s_barrier();
        if (t < 15) stage_ab(w1p, t + 1);
        else if (pi < 7) stage_ab(w1p + 65536, 0);
        bf16x8 av[4], bv[2];
#pragma unroll
        for (int nf = 0; nf < 4; ++nf) {
          const int n = wn2 * 64 + nf * 16 + lr;
          av[nf] = *(const bf16x8*)&w1_s[cur][n * 32 + ((lq ^ ((n >> 1) & 3)) << 3)];
        }
#pragma unroll
        for (int rf = 0; rf < 2; ++rf) {
          const int r = wr2 * 32 + rf * 16 + lr;
          bv[rf] = *(const bf16x8*)&prim_s[cur][r * 32 + ((lq ^ ((r >> 1) & 3)) << 3)];
        }
#pragma unroll
        for (int nf = 0; nf < 4; ++nf)
#pragma unroll
          for (int rf = 0; rf < 2; ++rf)
            acc1[nf][rf] = __builtin_amdgcn_mfma_f32_16x16x32_bf16(av[nf], bv[rf], acc1[nf][rf], 0, 0, 0);
      }

      // h write (ds_write); visible via lgkmcnt only (global stages stay in flight)
#pragma unroll
      for (int nf = 0; nf < 4; ++nf) {
        const int n0 = wn2 * 64 + nf * 16 + (lq << 2);
        const float4 bb = pb1v[nf];
#pragma unroll
        for (int rf = 0; rf < 2; ++rf) {
          const int row = wr2 * 32 + rf * 16 + lr;
          uint2 pk;
          pk.x = pack_bf2(fmaxf(acc1[nf][rf][0] + bb.x, 0.0f),
                          fmaxf(acc1[nf][rf][1] + bb.y, 0.0f));
          pk.y = pack_bf2(fmaxf(acc1[nf][rf][2] + bb.z, 0.0f),
                          fmaxf(acc1[nf][rf][3] + bb.w, 0.0f));
          *(uint2*)&h_s[row * 128 + (((n0 >> 3) ^ (row & 7)) << 3) + (n0 & 7)] = pk;
        }
      }
      asm volatile("s_waitcnt lgkmcnt(0)" ::: "memory");
      __builtin_amdgcn_s_barrier();

      // phase 2: contract this half's 128 n
      {
        const int dmu = wn2 * 16;
        const int row_a = wr2 * 32;
#pragma unroll
        for (int kc8 = 0; kc8 < 4; ++kc8) {
          const int slot = ((kc8 << 2) + lq) ^ (lr & 7);
          const bf16x8 amu = *(const bf16x8*)&pw2_s[(dmu + lr) * 128 + (slot << 3)];
          const bf16x8 als = *(const bf16x8*)&pw2_s[(dmu + 32 + lr) * 128 + (slot << 3)];
          const bf16x8 b0 = *(const bf16x8*)&h_s[(row_a + lr) * 128 + (slot << 3)];
          const bf16x8 b1 = *(const bf16x8*)&h_s[(row_a + 16 + lr) * 128 + (slot << 3)];
          acc2[0][0] = __builtin_amdgcn_mfma_f32_16x16x32_bf16(amu, b0, acc2[0][0], 0, 0, 0);
          acc2[0][1] = __builtin_amdgcn_mfma_f32_16x16x32_bf16(als, b0, acc2[0][1], 0, 0, 0);
          acc2[1][0] = __builtin_amdgcn_mfma_f32_16x16x32_bf16(amu, b1, acc2[1][0], 0, 0, 0);
          acc2[1][1] = __builtin_amdgcn_mfma_f32_16x16x32_bf16(als, b1, acc2[1][1], 0, 0, 0);
        }
      }
      asm volatile("s_waitcnt lgkmcnt(0)" ::: "memory");
      __builtin_amdgcn_s_barrier();   // all reads of h_s/pw2_s retired before overwrite
      if (half == 0) stage_pw2(w2p, 1);
      else if (pi < 7) stage_pw2(w2p + 16384, 0);
    }

    // per-p epilogue: accumulate iv and iv*mu into registers
    {
      const int d0 = wn2 * 16 + (lq << 2);
      const int row_a = wr2 * 32;
      const float4 b2mu = *(const float4*)(pb2 + p * 64 + d0);
      const float4 b2ls = *(const float4*)(pb2 + p * 64 + 32 + d0);
      const float wp0 = wgt[(size_t)(row0 + row_a + lr) * 16 + p];
      const float wp1 = wgt[(size_t)(row0 + row_a + 16 + lr) * 16 + p];
#pragma unroll
      for (int s = 0; s < 2; ++s) {
        const float wp = s ? wp1 : wp0;
        const float mu0 = acc2[s][0][0] + b2mu.x, ls0 = acc2[s][1][0] + b2ls.x;
        const float mu1 = acc2[s][0][1] + b2mu.y, ls1 = acc2[s][1][1] + b2ls.y;
        const float mu2 = acc2[s][0][2] + b2mu.z, ls2 = acc2[s][1][2] + b2ls.z;
        const float mu3 = acc2[s][0][3] + b2mu.w, ls3 = acc2[s][1][3] + b2ls.w;
        const float iv0 = wp * __expf(-ls0), iv1 = wp * __expf(-ls1);
        const float iv2 = wp * __expf(-ls2), iv3 = wp * __expf(-ls3);
        num[s][0] += iv0 * mu0; num[s][1] += iv1 * mu1;
        num[s][2] += iv2 * mu2; num[s][3] += iv3 * mu3;
        den[s][0] += iv0; den[s][1] += iv1;
        den[s][2] += iv2; den[s][3] += iv3;
      }
    }
  }

  // final write: fp32 partial sums for this p-group
  {
    const int d0 = wn2 * 16 + (lq << 2);
    const int row_a = wr2 * 32;
#pragma unroll
    for (int s = 0; s < 2; ++s) {
      const int row_g = row0 + row_a + s * 16 + lr;
      float* ob = outbuf + ((size_t)row_g * 2 + pg) * 64;
      *(f32x4*)(ob + d0) = num[s];
      *(f32x4*)(ob + 32 + d0) = den[s];
    }
  }
}

// ---------------- mixture finish: mean = (num0+num1)/(den0+den1) ----------------

__global__ __launch_bounds__(256) void mix_finish_k(const float* __restrict__ buf,  // [B][2][64]
                                                    float* __restrict__ mean_out) { // [B][32]
  const int gid = blockIdx.x * 256 + threadIdx.x;
  const int row = gid >> 3;
  const int a0 = (gid & 7) * 4;
  const float* rp = buf + (size_t)row * 128;
  const f32x4 n0 = *(const f32x4*)(rp + a0);
  const f32x4 d0 = *(const f32x4*)(rp + 32 + a0);
  const f32x4 n1 = *(const f32x4*)(rp + 64 + a0);
  const f32x4 d1 = *(const f32x4*)(rp + 96 + a0);
  f32x4 res;
  res[0] = (n0[0] + n1[0]) / (d0[0] + d1[0]);
  res[1] = (n0[1] + n1[1]) / (d0[1] + d1[1]);
  res[2] = (n0[2] + n1[2]) / (d0[2] + d1[2]);
  res[3] = (n0[3] + n1[3]) / (d0[3] + d1[3]);
  *(f32x4*)(mean_out + (size_t)row * 32 + a0) = res;
}

// ---------------- launcher ----------------

extern "C" void kernel_launch(void* const* d_in, const int* in_sizes, int n_in,
                              void* d_out, int out_size, void* d_ws, size_t ws_size,
                              hipStream_t stream) {
  const float* features = (const float*)d_in[0];
  const float* se_w1 = (const float*)d_in[1];
  const float* se_b1 = (const float*)d_in[2];
  const float* se_w2 = (const float*)d_in[3];
  const float* se_b2 = (const float*)d_in[4];
  const float* ge_w1 = (const float*)d_in[5];
  const float* ge_b1 = (const float*)d_in[6];
  const float* ge_w2 = (const float*)d_in[7];
  const float* ge_b2 = (const float*)d_in[8];
  const float* gt_w1 = (const float*)d_in[9];
  const float* gt_b1 = (const float*)d_in[10];
  const float* gt_w2 = (const float*)d_in[11];
  const float* gt_b2 = (const float*)d_in[12];
  const float* pse_w1 = (const float*)d_in[13];
  const float* pse_b1 = (const float*)d_in[14];
  const float* pse_w2 = (const float*)d_in[15];
  const float* pse_b2 = (const float*)d_in[16];
  const float* pw1 = (const float*)d_in[17];
  const float* pb1 = (const float*)d_in[18];
  const float* pw2 = (const float*)d_in[19];
  const float* pb2 = (const float*)d_in[20];
  const float* vf_w1 = (const float*)d_in[21];
  const float* vf_b1 = (const float*)d_in[22];
  const float* vf_w2 = (const float*)d_in[23];
  const float* vf_b2 = (const float*)d_in[24];
  (void)in_sizes; (void)n_in; (void)out_size; (void)ws_size;

  char* base = (char*)d_ws;
  size_t off = 0;
  auto alloc = [&](size_t bytes) -> char* {
    char* p = base + off;
    off += (bytes + 255) & ~(size_t)255;
    return p;
  };
  unsigned short* fbf     = (unsigned short*)alloc((size_t)NB * 640 * 2);
  unsigned short* bufA    = (unsigned short*)alloc((size_t)NB * 1024 * 2);  // s1|p1, then v1
  unsigned short* g1      = (unsigned short*)alloc((size_t)NB * 512 * 2);
  unsigned short* gate_in = (unsigned short*)alloc((size_t)NB * 512 * 2);
  unsigned short* gate_h  = (unsigned short*)alloc((size_t)NB * 256 * 2);
  unsigned short* prim    = (unsigned short*)alloc((size_t)NB * 256 * 2);
  float* wgt              = (float*)alloc((size_t)NB * 16 * 4);
  unsigned short* wcat1t  = (unsigned short*)alloc((size_t)1024 * 512 * 2);  // [se_w1t | pse_w1t]
  float* bcat1            = (float*)alloc(1024 * 4);
  unsigned short* se_w2t  = (unsigned short*)alloc(256 * 512 * 2);
  unsigned short* ge_w1t  = (unsigned short*)alloc(512 * 128 * 2);
  unsigned short* ge_w2t  = (unsigned short*)alloc(256 * 512 * 2);
  unsigned short* gt_w1t  = (unsigned short*)alloc(256 * 512 * 2);
  unsigned short* pse_w2t = (unsigned short*)alloc(256 * 512 * 2);
  unsigned short* pw1t    = (unsigned short*)alloc((size_t)16 * 256 * 256 * 2);
  unsigned short* pw2t    = (unsigned short*)alloc((size_t)16 * 64 * 256 * 2);
  unsigned short* vf_w1t  = (unsigned short*)alloc(1024 * 640 * 2);
  unsigned short* vf_w2t  = (unsigned short*)alloc(512 * 1024 * 2);

  unsigned short* se_w1t  = wcat1t;                 // rows 0-511
  unsigned short* pse_w1t = wcat1t + 512 * 512;     // rows 512-1023

  // outbuf [B][2][64] fp32 = 16MB, overlaid on bufA (dead by then).
  float* outbuf = (float*)bufA;

  float* mean_out = (float*)d_out;
  float* value_out = (float*)d_out + (size_t)NB * 32;

  fconv_k<<<dim3(10240), dim3(256), 0, stream>>>(features, fbf);
  bcat_k<<<dim3(4), dim3(256), 0, stream>>>(se_b1, pse_b1, bcat1);

  TJobs jobs;
  auto setj = [&](int i, const float* s, unsigned short* d, int K, int N, int b) {
    jobs.src[i] = s; jobs.dst[i] = d; jobs.K[i] = K; jobs.N[i] = N; jobs.batch[i] = b;
  };
  setj(0, se_w1, se_w1t, 512, 512, 1);
  setj(1, se_w2, se_w2t, 512, 256, 1);
  setj(2, ge_w1, ge_w1t, 128, 512, 1);
  setj(3, ge_w2, ge_w2t, 512, 256, 1);
  setj(4, gt_w1, gt_w1t, 512, 256, 1);
  setj(5, pse_w1, pse_w1t, 512, 512, 1);
  setj(6, pse_w2, pse_w2t, 512, 256, 1);
  setj(7, pw1, pw1t, 256, 256, 16);
  setj(8, pw2, pw2t, 256, 64, 16);
  setj(9, vf_w1, vf_w1t, 640, 1024, 1);
  setj(10, vf_w2, vf_w2t, 1024, 512, 1);
  wtrans_k<<<dim3(1024, 11), dim3(256), 0, stream>>>(jobs);

  // DUAL-WIDE: [s1|p1] = relu(state @ wcat + bcat) (N=1024, K=512, 1024 wg)
  //         || g1 = relu(goal @ ge_w1 + b)          (N=512, K=128, 512 wg)
  gemm2_dual_k<<<dim3(1536), dim3(256), 0, stream>>>(
      fbf, 640, wcat1t, bcat1, bufA, 1024, 512, 2, 1024,
      fbf + 512, 640, ge_w1t, ge_b1, g1, 512, 128, 1, 512);
  // DUAL: gate_in[:,0:256] = relu(s1 @ se_w2 + b)  ||  gate_in[:,256:512] = relu(g1 @ ge_w2 + b)
  gemm3_dual_k<<<dim3(1024), dim3(256), 0, stream>>>(
      bufA, 1024, se_w2t, se_b2, gate_in, 512,
      g1, 512, ge_w2t, ge_b2, gate_in + 256, 512);
  // DUAL: gate_h = relu(gate_in @ gt_w1 + b)  ||  prim = relu(p1 @ pse_w2 + b)
  gemm3_dual_k<<<dim3(1024), dim3(256), 0, stream>>>(
      gate_in, 512, gt_w1t, gt_b1, gate_h, 256,
      bufA + 512, 1024, pse_w2t, pse_b2, prim, 256);
  // weights = sigmoid(gate_h @ gt_w2 + b)
  gt2_k<<<dim3(2048), dim3(256), 0, stream>>>(gate_h, gt_w2, gt_b2, wgt);
  // v1 = relu(features @ vf_w1 + b)         N=1024: gemm2 (bufA now dead -> reuse)
  gemm2_k<true><<<dim3(1024), dim3(256), 0, stream>>>(fbf, 640, vf_w1t, vf_b1, bufA, 1024, 640, 2);
  // value = relu(v1 @ vf_w2 + b) (fp32 out) N=512: gemm2
  gemm2_k<false><<<dim3(512), dim3(256), 0, stream>>>(bufA, 1024, vf_w2t, vf_b2, value_out, 512, 1024, 1);
  // mean head: 512 blocks (2/CU, all co-resident), 8 p's per block
  prim_head_k<<<dim3(256, 2), dim3(512), 0, stream>>>(prim, wgt, pw1t, pb1, pw2t, pb2, outbuf);
  // reduce the 2 p-group partials
  mix_finish_k<<<dim3(1024), dim3(256), 0, stream>>>(outbuf, mean_out);
}